// Round 9
// baseline (79.741 us; speedup 1.0000x reference)
//
#include <hip/hip_runtime.h>
#include <hip/hip_fp16.h>

// Problem constants (match reference)
constexpr int Bc = 64;
constexpr int Nc = 32768;
constexpr int Kc = 128;
constexpr int Tc = 512;      // trajectory length
constexpr int TMAXc = 512;   // table time dim (== Tc)
constexpr int BK = Bc * Kc;  // 8192

typedef float f32x4 __attribute__((ext_vector_type(4)));
typedef float f32x2 __attribute__((ext_vector_type(2)));

// Workspace layout:
//   [0, 16777216)        table    (B,K,TMAX) half2 (4 B/slot)
//   [16777216, +8192)    partials 1024 x float2
//   [16785408, +4)       counter  uint32
constexpr size_t TABLE_BYTES = (size_t)BK * TMAXc * 4;
constexpr int NBLK1 = BK / 2;   // 4096 blocks, 2 (b,k) pairs each
constexpr int NBLK2 = 1024;

// ---------------- Phase 1: scatter traj xy into (B,K,TMAX) half2 table ------
// Two contiguous (b,k) pairs per block (exact 5-iter load balance), XCD
// affinity b % 8 == blockIdx % 8 so each b-slice is built in one XCD's L2.
// times is a permutation of 0..511 per (b,k): every slot is written.
__global__ __launch_bounds__(256) void build_table_k(
    const f32x4* __restrict__ traj4,   // (B,K,T,5) viewed as f32x4[BK*640]
    uint2* __restrict__ table2,        // (B,K,TMAX) half2 viewed as uint2[BK*256]
    unsigned* __restrict__ counter)
{
    __shared__ __align__(16) float    stage[2 * Tc * 5];  // 20480 B
    __shared__ __align__(8)  unsigned tbl[2 * TMAXc];     //  4096 B

    const int j   = blockIdx.x;
    if (j == 0 && threadIdx.x == 0) *counter = 0u;  // reset for phase-2 finish
    const int xcd = j & 7;
    const int s   = j >> 3;                  // 0..511
    const int b   = ((s >> 6) << 3) | xcd;   // 0..63, b%8 == xcd
    const int k2  = s & 63;                  // pair-of-k index
    const int bk0 = (b << 7) | (k2 << 1);    // first of two contiguous (b,k)

    // coalesced nt load: 1280 f32x4 per block = exactly 5 per thread
    const f32x4* src = traj4 + (size_t)bk0 * 640;
    #pragma unroll
    for (int r = 0; r < 5; ++r) {
        int t = threadIdx.x + r * 256;
        ((f32x4*)stage)[t] = __builtin_nontemporal_load(&src[t]);
    }
    __syncthreads();

    // scatter 1024 records within LDS
    #pragma unroll
    for (int r = 0; r < 4; ++r) {
        int t = threadIdx.x + r * 256;         // 0..1023; pair = t>>9
        float x  = stage[t * 5 + 0];
        float y  = stage[t * 5 + 1];
        float tv = stage[t * 5 + 4];
        int tau = __float2int_rn(tv * 10.0f);      // matches jnp.round(...)
        if ((unsigned)tau < (unsigned)TMAXc) {     // mode='drop'
            __half2 p = __floats2half2_rn(x, y);
            unsigned raw;
            __builtin_memcpy(&raw, &p, 4);
            tbl[((t >> 9) << 9) + tau] = raw;
        }
    }
    __syncthreads();

    // coalesced cached store: 512 uint2 = exactly 2 per thread
    uint2* dst = table2 + (size_t)bk0 * 256;
    #pragma unroll
    for (int r = 0; r < 2; ++r) {
        int t = threadIdx.x + r * 256;
        dst[t] = ((const uint2*)tbl)[t];
    }
}

// ------- Phase 2: gather + reduce; last block folds partials -> loss --------
// XCD affinity: block j handles batch b with b%8 == j%8; gathers stay in this
// XCD's 8 b-slices (2 MB, L2/L3-resident). Branchless, 8 gathers in flight.
// Last-block finish is cheap HERE (unlike R4's fused kernel): at fence time
// this kernel's dirty L2 is ~8 B/block of partials — the table was written
// back at phase-1 kernel end — so __threadfence() has almost nothing to flush.
__global__ __launch_bounds__(256) void gather_reduce_k(
    const f32x2*    __restrict__ state2,  // (B,N,4) viewed as f32x2 pairs
    const int*      __restrict__ tidx,    // (B,N)
    const int*      __restrict__ uid,     // (B,N)
    const unsigned* __restrict__ table,   // (B,K,TMAX) half2 as u32
    float2*         __restrict__ partials,
    unsigned*       __restrict__ counter,
    float*          __restrict__ out)
{
    const int j     = blockIdx.x;
    const int xcd   = j & 7;
    const int s     = j >> 3;                 // 0..127
    const int b     = ((s >> 4) << 3) | xcd;  // 0..63, b%8 == xcd
    const int chunk = s & 15;                 // 0..15
    const int base  = (b << 15) + (chunk << 11);   // 2048 items per block
    const unsigned* tb = table + ((long long)b << 16);

    f32x2    sv[8];
    int      idv[8], tiv[8];
    unsigned tg[8];

    // 1) stream loads (nt: read-once, don't evict table from L2)
    #pragma unroll
    for (int r = 0; r < 8; ++r) {
        int i = base + r * 256 + threadIdx.x;
        sv[r]  = __builtin_nontemporal_load(&state2[2 * (size_t)i]);  // xy only
        idv[r] = __builtin_nontemporal_load(&uid[i]);
        tiv[r] = __builtin_nontemporal_load(&tidx[i]);
    }
    // 2) 8 independent unconditional gathers (clamped addr is always valid)
    #pragma unroll
    for (int r = 0; r < 8; ++r) {
        int obj = min(max(idv[r], 0), Kc - 1);
        int tcl = min(max(tiv[r], 0), TMAXc - 1);
        tg[r] = tb[(obj << 9) + tcl];
    }
    // 3) predicated accumulate
    float sum = 0.0f, cnt = 0.0f;
    #pragma unroll
    for (int r = 0; r < 8; ++r) {
        __half2 p;
        __builtin_memcpy(&p, &tg[r], 4);
        float tx = __low2float(p);
        float ty = __high2float(p);
        if (idv[r] >= 0) {
            sum += fabsf(sv[r].x - tx) + fabsf(sv[r].y - ty);
            cnt += 1.0f;
        }
    }

    // wave64 down-reduce, then cross-wave via LDS
    #pragma unroll
    for (int off = 32; off > 0; off >>= 1) {
        sum += __shfl_down(sum, off, 64);
        cnt += __shfl_down(cnt, off, 64);
    }
    __shared__ float2 lred[4];
    const int lane = threadIdx.x & 63;
    const int w    = threadIdx.x >> 6;
    if (lane == 0) lred[w] = make_float2(sum, cnt);
    __syncthreads();

    __shared__ unsigned is_last;
    if (threadIdx.x == 0) {
        float s2 = 0.0f, c2 = 0.0f;
        #pragma unroll
        for (int q = 0; q < 4; ++q) { s2 += lred[q].x; c2 += lred[q].y; }
        partials[j] = make_float2(s2, c2);
        __threadfence();                       // release partial (tiny flush)
        unsigned old = atomicAdd(counter, 1u); // device-scope (m20)
        is_last = (old == (unsigned)(NBLK2 - 1)) ? 1u : 0u;
    }
    __syncthreads();
    if (!is_last) return;

    // Last block: deterministic fixed-order fold of 1024 partials.
    __threadfence();                           // acquire
    float s2 = 0.0f, c2 = 0.0f;
    #pragma unroll
    for (int r = 0; r < 4; ++r) {
        float2 p = partials[threadIdx.x + r * 256];
        s2 += p.x; c2 += p.y;
    }
    #pragma unroll
    for (int off = 32; off > 0; off >>= 1) {
        s2 += __shfl_down(s2, off, 64);
        c2 += __shfl_down(c2, off, 64);
    }
    __shared__ float2 lred2[4];
    if (lane == 0) lred2[w] = make_float2(s2, c2);
    __syncthreads();
    if (threadIdx.x == 0) {
        float s3 = 0.0f, c3 = 0.0f;
        #pragma unroll
        for (int q = 0; q < 4; ++q) { s3 += lred2[q].x; c3 += lred2[q].y; }
        out[0] = s3 / c3;
    }
}

extern "C" void kernel_launch(void* const* d_in, const int* in_sizes, int n_in,
                              void* d_out, int out_size, void* d_ws, size_t ws_size,
                              hipStream_t stream) {
    const f32x2* state2 = (const f32x2*)d_in[0];   // (B,N,4) f32
    const int*   tidx   = (const int*)  d_in[1];   // (B,N)   i32
    const int*   uid    = (const int*)  d_in[2];   // (B,N)   i32
    const f32x4* traj4  = (const f32x4*)d_in[3];   // (B,K,T,5) f32
    float* out = (float*)d_out;

    unsigned* table    = (unsigned*)d_ws;
    float2*   partials = (float2*)((char*)d_ws + TABLE_BYTES);
    unsigned* counter  = (unsigned*)((char*)d_ws + TABLE_BYTES + NBLK2 * 8);

    build_table_k  <<<NBLK1, 256, 0, stream>>>(traj4, (uint2*)table, counter);
    gather_reduce_k<<<NBLK2, 256, 0, stream>>>(state2, tidx, uid, table,
                                               partials, counter, out);
}

// Round 10
// 43.257 us; speedup vs baseline: 1.8434x; 1.8434x over previous
//
#include <hip/hip_runtime.h>
#include <hip/hip_fp16.h>

// Problem constants (match reference)
constexpr int Bc = 64;
constexpr int Nc = 32768;
constexpr int Kc = 128;
constexpr int Tc = 512;      // trajectory length
constexpr int TMAXc = 512;   // table time dim (== Tc)
constexpr int BK = Bc * Kc;  // 8192

typedef float f32x4 __attribute__((ext_vector_type(4)));
typedef float f32x2 __attribute__((ext_vector_type(2)));

// Workspace layout:
//   [0, 16777216)        table    (B,K,TMAX) half2 (4 B/slot)
//   [16777216, +16384)   partials 2048 x float2
constexpr size_t TABLE_BYTES = (size_t)BK * TMAXc * 4;
constexpr int NBLK1 = BK / 2;   // 4096 blocks, 2 (b,k) pairs each
constexpr int NBLK2 = 2048;     // 8 blocks/CU -> 32 waves/CU (latency hiding)

// ---------------- Phase 1: scatter traj xy into (B,K,TMAX) half2 table ------
// Two contiguous (b,k) pairs per block (exact 5-iter load balance), XCD
// affinity b % 8 == blockIdx % 8 so each b-slice is built in one XCD's L2.
// times is a permutation of 0..511 per (b,k): every slot is written.
// Measured at ~14 us = its 101 MB roofline (R9).
__global__ __launch_bounds__(256) void build_table_k(
    const f32x4* __restrict__ traj4,   // (B,K,T,5) viewed as f32x4[BK*640]
    uint2* __restrict__ table2)        // (B,K,TMAX) half2 viewed as uint2[BK*256]
{
    __shared__ __align__(16) float    stage[2 * Tc * 5];  // 20480 B
    __shared__ __align__(8)  unsigned tbl[2 * TMAXc];     //  4096 B

    const int j   = blockIdx.x;
    const int xcd = j & 7;
    const int s   = j >> 3;                  // 0..511
    const int b   = ((s >> 6) << 3) | xcd;   // 0..63, b%8 == xcd
    const int k2  = s & 63;                  // pair-of-k index
    const int bk0 = (b << 7) | (k2 << 1);    // first of two contiguous (b,k)

    // coalesced nt load: 1280 f32x4 per block = exactly 5 per thread
    const f32x4* src = traj4 + (size_t)bk0 * 640;
    #pragma unroll
    for (int r = 0; r < 5; ++r) {
        int t = threadIdx.x + r * 256;
        ((f32x4*)stage)[t] = __builtin_nontemporal_load(&src[t]);
    }
    __syncthreads();

    // scatter 1024 records within LDS
    #pragma unroll
    for (int r = 0; r < 4; ++r) {
        int t = threadIdx.x + r * 256;         // 0..1023; pair = t>>9
        float x  = stage[t * 5 + 0];
        float y  = stage[t * 5 + 1];
        float tv = stage[t * 5 + 4];
        int tau = __float2int_rn(tv * 10.0f);      // matches jnp.round(...)
        if ((unsigned)tau < (unsigned)TMAXc) {     // mode='drop'
            __half2 p = __floats2half2_rn(x, y);
            unsigned raw;
            __builtin_memcpy(&raw, &p, 4);
            tbl[((t >> 9) << 9) + tau] = raw;
        }
    }
    __syncthreads();

    // coalesced cached store: 512 uint2 = exactly 2 per thread
    uint2* dst = table2 + (size_t)bk0 * 256;
    #pragma unroll
    for (int r = 0; r < 2; ++r) {
        int t = threadIdx.x + r * 256;
        dst[t] = ((const uint2*)tbl)[t];
    }
}

// ---------------- Phase 2: gather + per-block partial reduction -------------
// Latency-bound (R9: VALU idle, 0.5 TB/s with low occupancy), so: 8 blocks/CU
// of TLP, and gathers issued BEFORE the state stream loads so the L2/L3
// round-trip overlaps them. XCD affinity keeps gathers in the local L2.
// NO fences/atomics here — R4/R9 both showed device-scope release sequences
// cost 45-80 us in this kernel.
__global__ __launch_bounds__(256) void gather_reduce_k(
    const f32x2*    __restrict__ state2,  // (B,N,4) viewed as f32x2 pairs
    const int*      __restrict__ tidx,    // (B,N)
    const int*      __restrict__ uid,     // (B,N)
    const unsigned* __restrict__ table,   // (B,K,TMAX) half2 as u32
    float2*         __restrict__ partials)
{
    const int j     = blockIdx.x;
    const int xcd   = j & 7;
    const int s     = j >> 3;                 // 0..255
    const int b     = ((s >> 5) << 3) | xcd;  // 0..63, b%8 == xcd
    const int chunk = s & 31;                 // 0..31
    const int base  = (b << 15) + (chunk << 10);   // 1024 items per block
    const unsigned* tb = table + ((long long)b << 16);

    int      idv[4], tiv[4];
    unsigned tg[4];
    f32x2    sv[4];

    // 1) index streams first
    #pragma unroll
    for (int r = 0; r < 4; ++r) {
        int i = base + r * 256 + threadIdx.x;
        idv[r] = __builtin_nontemporal_load(&uid[i]);
        tiv[r] = __builtin_nontemporal_load(&tidx[i]);
    }
    // 2) issue gathers (clamped addr always valid) — overlap with state loads
    #pragma unroll
    for (int r = 0; r < 4; ++r) {
        int obj = min(max(idv[r], 0), Kc - 1);
        int tcl = min(max(tiv[r], 0), TMAXc - 1);
        tg[r] = tb[(obj << 9) + tcl];
    }
    // 3) state xy streams (not needed until accumulate)
    #pragma unroll
    for (int r = 0; r < 4; ++r) {
        int i = base + r * 256 + threadIdx.x;
        sv[r] = __builtin_nontemporal_load(&state2[2 * (size_t)i]);
    }
    // 4) predicated accumulate
    float sum = 0.0f, cnt = 0.0f;
    #pragma unroll
    for (int r = 0; r < 4; ++r) {
        __half2 p;
        __builtin_memcpy(&p, &tg[r], 4);
        float tx = __low2float(p);
        float ty = __high2float(p);
        if (idv[r] >= 0) {
            sum += fabsf(sv[r].x - tx) + fabsf(sv[r].y - ty);
            cnt += 1.0f;
        }
    }

    // wave64 down-reduce, then cross-wave via LDS
    #pragma unroll
    for (int off = 32; off > 0; off >>= 1) {
        sum += __shfl_down(sum, off, 64);
        cnt += __shfl_down(cnt, off, 64);
    }
    __shared__ float2 lred[4];
    const int lane = threadIdx.x & 63;
    const int w    = threadIdx.x >> 6;
    if (lane == 0) lred[w] = make_float2(sum, cnt);
    __syncthreads();
    if (threadIdx.x == 0) {
        float s2 = 0.0f, c2 = 0.0f;
        #pragma unroll
        for (int q = 0; q < 4; ++q) { s2 += lred[q].x; c2 += lred[q].y; }
        partials[j] = make_float2(s2, c2);
    }
}

// ---------------- Phase 3: deterministic final reduce -> loss ---------------
__global__ __launch_bounds__(1024) void final_reduce_k(
    const float2* __restrict__ partials, float* __restrict__ out)
{
    float s = 0.0f, c = 0.0f;
    #pragma unroll
    for (int r = 0; r < 2; ++r) {
        float2 p = partials[threadIdx.x + r * 1024];   // 2048 partials
        s += p.x; c += p.y;
    }
    #pragma unroll
    for (int off = 32; off > 0; off >>= 1) {
        s += __shfl_down(s, off, 64);
        c += __shfl_down(c, off, 64);
    }
    __shared__ float2 lds[16];
    int lane = threadIdx.x & 63;
    int w    = threadIdx.x >> 6;
    if (lane == 0) lds[w] = make_float2(s, c);
    __syncthreads();
    if (threadIdx.x == 0) {
        float s2 = 0.0f, c2 = 0.0f;
        #pragma unroll
        for (int q = 0; q < 16; ++q) { s2 += lds[q].x; c2 += lds[q].y; }
        out[0] = s2 / c2;
    }
}

extern "C" void kernel_launch(void* const* d_in, const int* in_sizes, int n_in,
                              void* d_out, int out_size, void* d_ws, size_t ws_size,
                              hipStream_t stream) {
    const f32x2* state2 = (const f32x2*)d_in[0];   // (B,N,4) f32
    const int*   tidx   = (const int*)  d_in[1];   // (B,N)   i32
    const int*   uid    = (const int*)  d_in[2];   // (B,N)   i32
    const f32x4* traj4  = (const f32x4*)d_in[3];   // (B,K,T,5) f32
    float* out = (float*)d_out;

    unsigned* table    = (unsigned*)d_ws;
    float2*   partials = (float2*)((char*)d_ws + TABLE_BYTES);

    build_table_k  <<<NBLK1, 256, 0, stream>>>(traj4, (uint2*)table);
    gather_reduce_k<<<NBLK2, 256, 0, stream>>>(state2, tidx, uid, table, partials);
    final_reduce_k <<<1, 1024, 0, stream>>>(partials, out);
}

// Round 11
// 39.620 us; speedup vs baseline: 2.0127x; 1.0918x over previous
//
#include <hip/hip_runtime.h>
#include <hip/hip_fp16.h>

// Problem constants (match reference)
constexpr int Bc = 64;
constexpr int Nc = 32768;
constexpr int Kc = 128;
constexpr int Tc = 512;      // trajectory length
constexpr int TMAXc = 512;   // table time dim (== Tc)
constexpr int BK = Bc * Kc;  // 8192

typedef float f32x4 __attribute__((ext_vector_type(4)));
typedef float f32x2 __attribute__((ext_vector_type(2)));
typedef int   i32x2 __attribute__((ext_vector_type(2)));

// Workspace layout:
//   [0, 16777216)        table    (B,K,TMAX) half2 (4 B/slot)
//   [16777216, +4096)    partials 512 x float2
constexpr size_t TABLE_BYTES = (size_t)BK * TMAXc * 4;
constexpr int NBLK1 = BK / 2;   // 4096 blocks, 2 (b,k) pairs each
constexpr int NBLK2 = 512;      // measured-best p2 geometry (R7): 16 items/thread

// ---------------- Phase 1: scatter traj xy into (B,K,TMAX) half2 table ------
// Two contiguous (b,k) pairs per block (exact 5-iter load balance), XCD
// affinity b % 8 == blockIdx % 8 so each b-slice is built in one XCD's L2.
// times is a permutation of 0..511 per (b,k): every slot is written.
// Measured ~14 us = its 101 MB roofline (R9 decomposition) — done.
__global__ __launch_bounds__(256) void build_table_k(
    const f32x4* __restrict__ traj4,   // (B,K,T,5) viewed as f32x4[BK*640]
    uint2* __restrict__ table2)        // (B,K,TMAX) half2 viewed as uint2[BK*256]
{
    __shared__ __align__(16) float    stage[2 * Tc * 5];  // 20480 B
    __shared__ __align__(8)  unsigned tbl[2 * TMAXc];     //  4096 B

    const int j   = blockIdx.x;
    const int xcd = j & 7;
    const int s   = j >> 3;                  // 0..511
    const int b   = ((s >> 6) << 3) | xcd;   // 0..63, b%8 == xcd
    const int k2  = s & 63;                  // pair-of-k index
    const int bk0 = (b << 7) | (k2 << 1);    // first of two contiguous (b,k)

    // coalesced nt load: 1280 f32x4 per block = exactly 5 per thread
    const f32x4* src = traj4 + (size_t)bk0 * 640;
    #pragma unroll
    for (int r = 0; r < 5; ++r) {
        int t = threadIdx.x + r * 256;
        ((f32x4*)stage)[t] = __builtin_nontemporal_load(&src[t]);
    }
    __syncthreads();

    // scatter 1024 records within LDS
    #pragma unroll
    for (int r = 0; r < 4; ++r) {
        int t = threadIdx.x + r * 256;         // 0..1023; pair = t>>9
        float x  = stage[t * 5 + 0];
        float y  = stage[t * 5 + 1];
        float tv = stage[t * 5 + 4];
        int tau = __float2int_rn(tv * 10.0f);      // matches jnp.round(...)
        if ((unsigned)tau < (unsigned)TMAXc) {     // mode='drop'
            __half2 p = __floats2half2_rn(x, y);
            unsigned raw;
            __builtin_memcpy(&raw, &p, 4);
            tbl[((t >> 9) << 9) + tau] = raw;
        }
    }
    __syncthreads();

    // coalesced cached store: 512 uint2 = exactly 2 per thread
    uint2* dst = table2 + (size_t)bk0 * 256;
    #pragma unroll
    for (int r = 0; r < 2; ++r) {
        int t = threadIdx.x + r * 256;
        dst[t] = ((const uint2*)tbl)[t];
    }
}

// ---------------- Phase 2: gather + per-block partial reduction -------------
// ILP-bound (R6/R7/R10 trend: deeper per-thread batches win; TLP doesn't).
// 16 items/thread as 8 ADJACENT PAIRS: 8x f32x4 (state, 2 records) + 8x int2
// (uid) + 8x int2 (tidx) = 24 wide stream loads (was 48), then 16 independent
// gathers. XCD affinity keeps gathers in the local L2/L3 slice.
// NO fences/atomics — R4/R9: device-scope release costs 45-80 us here.
__global__ __launch_bounds__(256) void gather_reduce_k(
    const f32x4*    __restrict__ state4,  // (B,N,4) viewed as f32x4 records
    const i32x2*    __restrict__ tidx2,   // (B,N) as pairs
    const i32x2*    __restrict__ uid2,    // (B,N) as pairs
    const unsigned* __restrict__ table,   // (B,K,TMAX) half2 as u32
    float2*         __restrict__ partials)
{
    const int j     = blockIdx.x;
    const int xcd   = j & 7;
    const int s     = j >> 3;                 // 0..63
    const int b     = ((s >> 3) << 3) | xcd;  // 0..63, b%8 == xcd
    const int chunk = s & 7;                  // 0..7
    // pairs: 16384 per b, 2048 per chunk, 8 per thread
    const int bpair = (b << 14) + (chunk << 11);
    const unsigned* tb = table + ((long long)b << 16);

    f32x4    sv[8];      // xy0, vel-junk replaced: holds [x0,y0,x1,y1]? no: full record
    i32x2    idv[8], tiv[8];
    unsigned tg[16];

    // 1) wide stream loads (nt: read-once)
    #pragma unroll
    for (int r = 0; r < 8; ++r) {
        int p = bpair + r * 256 + threadIdx.x;
        sv[r]  = __builtin_nontemporal_load(&state4[p]);   // 2 records' xy? no:
        // state4[p] = record p's (x,y,vx,vy). We need TWO records per pair.
        idv[r] = __builtin_nontemporal_load(&uid2[p]);
        tiv[r] = __builtin_nontemporal_load(&tidx2[p]);
    }
    // NOTE: state is 16 B per ITEM, so one f32x4 covers ONE item, not two.
    // Load the second item of each pair now (still wide, coalesced):
    f32x2 sw[8];
    #pragma unroll
    for (int r = 0; r < 8; ++r) {
        int p = bpair + r * 256 + threadIdx.x;
        // item indices 2p and 2p+1; sv[r] holds item 2p's record (x,y,vx,vy)?
        // No: state4[p] is record p. Redo: we need records 2p and 2p+1.
        sw[r] = __builtin_nontemporal_load(
            (const f32x2*)&state4[2 * (size_t)p + 1]);     // item 2p+1 xy
    }
    #pragma unroll
    for (int r = 0; r < 8; ++r) {
        int p = bpair + r * 256 + threadIdx.x;
        sv[r] = __builtin_nontemporal_load(&state4[2 * (size_t)p]);  // item 2p rec
    }

    // 2) 16 independent gathers (clamped addr always valid)
    #pragma unroll
    for (int r = 0; r < 8; ++r) {
        int o0 = min(max(idv[r].x, 0), Kc - 1);
        int t0 = min(max(tiv[r].x, 0), TMAXc - 1);
        int o1 = min(max(idv[r].y, 0), Kc - 1);
        int t1 = min(max(tiv[r].y, 0), TMAXc - 1);
        tg[2 * r]     = tb[(o0 << 9) + t0];
        tg[2 * r + 1] = tb[(o1 << 9) + t1];
    }

    // 3) predicated accumulate
    float sum = 0.0f, cnt = 0.0f;
    #pragma unroll
    for (int r = 0; r < 8; ++r) {
        __half2 p0, p1;
        __builtin_memcpy(&p0, &tg[2 * r], 4);
        __builtin_memcpy(&p1, &tg[2 * r + 1], 4);
        if (idv[r].x >= 0) {
            sum += fabsf(sv[r].x - __low2float(p0)) + fabsf(sv[r].y - __high2float(p0));
            cnt += 1.0f;
        }
        if (idv[r].y >= 0) {
            sum += fabsf(sw[r].x - __low2float(p1)) + fabsf(sw[r].y - __high2float(p1));
            cnt += 1.0f;
        }
    }

    // wave64 down-reduce, then cross-wave via LDS
    #pragma unroll
    for (int off = 32; off > 0; off >>= 1) {
        sum += __shfl_down(sum, off, 64);
        cnt += __shfl_down(cnt, off, 64);
    }
    __shared__ float2 lred[4];
    const int lane = threadIdx.x & 63;
    const int w    = threadIdx.x >> 6;
    if (lane == 0) lred[w] = make_float2(sum, cnt);
    __syncthreads();
    if (threadIdx.x == 0) {
        float s2 = 0.0f, c2 = 0.0f;
        #pragma unroll
        for (int q = 0; q < 4; ++q) { s2 += lred[q].x; c2 += lred[q].y; }
        partials[j] = make_float2(s2, c2);
    }
}

// ---------------- Phase 3: deterministic final reduce -> loss ---------------
__global__ __launch_bounds__(512) void final_reduce_k(
    const float2* __restrict__ partials, float* __restrict__ out)
{
    float s, c;
    {
        float2 p = partials[threadIdx.x];   // exactly 512 partials
        s = p.x; c = p.y;
    }
    #pragma unroll
    for (int off = 32; off > 0; off >>= 1) {
        s += __shfl_down(s, off, 64);
        c += __shfl_down(c, off, 64);
    }
    __shared__ float2 lds[8];
    int lane = threadIdx.x & 63;
    int w    = threadIdx.x >> 6;
    if (lane == 0) lds[w] = make_float2(s, c);
    __syncthreads();
    if (threadIdx.x == 0) {
        float s2 = 0.0f, c2 = 0.0f;
        #pragma unroll
        for (int q = 0; q < 8; ++q) { s2 += lds[q].x; c2 += lds[q].y; }
        out[0] = s2 / c2;
    }
}

extern "C" void kernel_launch(void* const* d_in, const int* in_sizes, int n_in,
                              void* d_out, int out_size, void* d_ws, size_t ws_size,
                              hipStream_t stream) {
    const f32x4* state4 = (const f32x4*)d_in[0];   // (B,N,4) f32
    const i32x2* tidx2  = (const i32x2*)d_in[1];   // (B,N)   i32
    const i32x2* uid2   = (const i32x2*)d_in[2];   // (B,N)   i32
    const f32x4* traj4  = (const f32x4*)d_in[3];   // (B,K,T,5) f32
    float* out = (float*)d_out;

    unsigned* table    = (unsigned*)d_ws;
    float2*   partials = (float2*)((char*)d_ws + TABLE_BYTES);

    build_table_k  <<<NBLK1, 256, 0, stream>>>(traj4, (uint2*)table);
    gather_reduce_k<<<NBLK2, 256, 0, stream>>>(state4, tidx2, uid2, table, partials);
    final_reduce_k <<<1, 512, 0, stream>>>(partials, out);
}